// Round 1
// baseline (3252.195 us; speedup 1.0000x reference)
//
#include <hip/hip_runtime.h>
#include <hip/hip_bf16.h>

// FourierBlock: B=16, L=4096, H=3, E=512, M=128 selected modes.
// out[b,h,o,l] = irfft( scatter( einsum(rfft(q)[...,index], w) ) )
// Implemented as 3 dense stages (only 128 modes matter):
//   A: X[h,b,i,m]  = sum_l q[b,l,h,i] * (cos th, -sin th),  th = 2*pi*k_m*l/L
//   B: Y[h,b,o,m]  = sum_i X[h,b,i,m] * (wr + j*wi)[h,i,o,m];  scaled by c_m/L
//   C: out[b,h,o,l]= sum_m2 Yt[h,b,m2,o] * Tt[m2,l]
//
// ws layout (floats):
//   T2 : [4096][32 ms][4 jm][2 cs]            (1,048,576)  stage-A table
//   Tt : [256 m2][4096 l]                     (1,048,576)  stage-C table
//   X  : [3 h][16 b][512 i][128 m][2]         (6,291,456)
//   Yt : [3 h][16 b][256 m2][512 o]           (6,291,456)

#define L_TOT 4096
#define TWO_OVER_L (1.0f / 2048.0f)

__global__ __launch_bounds__(256) void build_t2(const int* __restrict__ index,
                                                float* __restrict__ T2) {
    const int idx = blockIdx.x * 256 + threadIdx.x;   // 1,048,576 total
    const int l  = idx >> 8;
    const int r  = idx & 255;
    const int ms = r >> 3;
    const int jm = (r >> 1) & 3;
    const int cs = r & 1;
    const int m  = jm * 32 + ms;
    const int k  = index[m];
    const int tt = (k * l) & (L_TOT - 1);
    const float x = (float)tt * TWO_OVER_L;           // angle in units of pi
    T2[idx] = cs ? -sinpif(x) : cospif(x);
}

__global__ __launch_bounds__(256) void build_tt(const int* __restrict__ index,
                                                float* __restrict__ Tt) {
    const int idx = blockIdx.x * 256 + threadIdx.x;   // 1,048,576 total
    const int m2 = idx >> 12;
    const int l  = idx & (L_TOT - 1);
    const int m  = m2 >> 1;
    const int k  = index[m];
    const int tt = (k * l) & (L_TOT - 1);
    const float x = (float)tt * TWO_OVER_L;
    Tt[idx] = (m2 & 1) ? -sinpif(x) : cospif(x);
}

// Stage A: grid 768 = b(16) x he_tile(48); block 256 = hs(8) x ms(32)
// thread computes acc[4 he][4 jm] complex; m = jm*32 + ms
__global__ __launch_bounds__(256) void stage_a(const float* __restrict__ q,
                                               const float* __restrict__ T2,
                                               float* __restrict__ X) {
    const int blk = blockIdx.x;
    const int b   = blk / 48;
    const int ht  = blk % 48;
    const int he0 = ht * 32;
    const int t   = threadIdx.x;
    const int ms  = t & 31;
    const int hs  = t >> 5;             // 0..7
    const int he  = he0 + hs * 4;

    float accR[4][4], accI[4][4];
#pragma unroll
    for (int a = 0; a < 4; ++a)
#pragma unroll
        for (int j = 0; j < 4; ++j) { accR[a][j] = 0.f; accI[a][j] = 0.f; }

    const float* qp = q + (size_t)b * L_TOT * 1536 + he;
    const float* tp = T2 + ms * 8;
#pragma unroll 2
    for (int l = 0; l < L_TOT; ++l) {
        const float4 qv = *reinterpret_cast<const float4*>(qp);
        const float4 t0 = *reinterpret_cast<const float4*>(tp);
        const float4 t1 = *reinterpret_cast<const float4*>(tp + 4);
        const float qa[4] = {qv.x, qv.y, qv.z, qv.w};
        const float cc[4] = {t0.x, t0.z, t1.x, t1.z};
        const float sn[4] = {t0.y, t0.w, t1.y, t1.w};
#pragma unroll
        for (int a = 0; a < 4; ++a)
#pragma unroll
            for (int j = 0; j < 4; ++j) {
                accR[a][j] = fmaf(qa[a], cc[j], accR[a][j]);
                accI[a][j] = fmaf(qa[a], sn[j], accI[a][j]);
            }
        qp += 1536; tp += 256;
    }
#pragma unroll
    for (int a = 0; a < 4; ++a) {
        const int hea = he + a;
        const int h = hea >> 9;
        const int i = hea & 511;
#pragma unroll
        for (int j = 0; j < 4; ++j) {
            const int m = j * 32 + ms;
            float2* xp = reinterpret_cast<float2*>(X) +
                         (((size_t)h * 16 + b) * 512 + i) * 128 + m;
            *xp = make_float2(accR[a][j], accI[a][j]);
        }
    }
}

// Stage B: grid 1536 = h(3) x mt(8) x oc(64); block 128 = b(16) x mp(8)
// thread: m = mt*16 + mp*2 (pair), o = oc*8 .. +7; acc[8 o][2 m] complex
__global__ __launch_bounds__(128) void stage_b(const float* __restrict__ X,
                                               const float* __restrict__ wr,
                                               const float* __restrict__ wi,
                                               const int* __restrict__ index,
                                               float* __restrict__ Yt) {
    const int blk = blockIdx.x;
    const int h  = blk >> 9;
    const int mt = (blk >> 6) & 7;
    const int oc = blk & 63;
    const int o0 = oc * 8;
    const int m0 = mt * 16;
    const int t  = threadIdx.x;
    const int b  = t >> 3;
    const int mp = t & 7;
    const int m  = m0 + mp * 2;

    float aR[8][2], aI[8][2];
#pragma unroll
    for (int oi = 0; oi < 8; ++oi) {
        aR[oi][0] = aR[oi][1] = 0.f;
        aI[oi][0] = aI[oi][1] = 0.f;
    }

    const float* xp  = X + ((((size_t)h * 16 + b) * 512) * 128 + m) * 2;
    const float* wrp = wr + ((size_t)h * 512 * 512 + o0) * 128 + m;
    const float* wip = wi + ((size_t)h * 512 * 512 + o0) * 128 + m;

    for (int i = 0; i < 512; ++i) {
        const float4 xv = *reinterpret_cast<const float4*>(xp);  // Xr0 Xi0 Xr1 Xi1
#pragma unroll
        for (int oi = 0; oi < 8; ++oi) {
            const float2 wrv = *reinterpret_cast<const float2*>(wrp + (size_t)oi * 128);
            const float2 wiv = *reinterpret_cast<const float2*>(wip + (size_t)oi * 128);
            aR[oi][0] = fmaf(xv.x, wrv.x, aR[oi][0]);
            aR[oi][0] = fmaf(-xv.y, wiv.x, aR[oi][0]);
            aI[oi][0] = fmaf(xv.x, wiv.x, aI[oi][0]);
            aI[oi][0] = fmaf(xv.y, wrv.x, aI[oi][0]);
            aR[oi][1] = fmaf(xv.z, wrv.y, aR[oi][1]);
            aR[oi][1] = fmaf(-xv.w, wiv.y, aR[oi][1]);
            aI[oi][1] = fmaf(xv.z, wiv.y, aI[oi][1]);
            aI[oi][1] = fmaf(xv.w, wrv.y, aI[oi][1]);
        }
        xp += 256; wrp += 65536; wip += 65536;
    }

    const int k0 = index[m];
    const int k1 = index[m + 1];
    const float s0 = (k0 == 0 ? 1.0f : 2.0f) * (1.0f / (float)L_TOT);
    const float s1 = (k1 == 0 ? 1.0f : 2.0f) * (1.0f / (float)L_TOT);
    // Yt[h][b][m2][o],  m2 rows 2m..2m+3 = (Yr0, Yi0, Yr1, Yi1)
    float* y0 = Yt + (((size_t)h * 16 + b) * 256 + 2 * m) * 512 + o0;
#pragma unroll
    for (int oi = 0; oi < 8; ++oi) {
        y0[oi]        = aR[oi][0] * s0;
        y0[512 + oi]  = aI[oi][0] * s0;
        y0[1024 + oi] = aR[oi][1] * s1;
        y0[1536 + oi] = aI[oi][1] * s1;
    }
}

// Stage C: grid 12288 = b(16) x h(3) x ot(16) x lt(16); block 256 = os(8) x ls(32)
// thread: acc[4 o][8 l]; K-loop over m2=256
__global__ __launch_bounds__(256) void stage_c(const float* __restrict__ Yt,
                                               const float* __restrict__ Tt,
                                               float* __restrict__ out) {
    const int blk = blockIdx.x;
    const int lt  = blk & 15;
    const int ot  = (blk >> 4) & 15;
    const int h   = (blk >> 8) % 3;
    const int b   = blk / 768;
    const int l0  = lt * 256;
    const int o0  = ot * 32;
    const int t   = threadIdx.x;
    const int ls  = t & 31;
    const int os  = t >> 5;   // 0..7

    float acc[4][8];
#pragma unroll
    for (int a = 0; a < 4; ++a)
#pragma unroll
        for (int j = 0; j < 8; ++j) acc[a][j] = 0.f;

    const float* yp = Yt + ((((size_t)h * 16 + b) * 256) * 512) + o0 + os * 4;
    const float* tp = Tt + l0 + ls;
#pragma unroll 2
    for (int m2 = 0; m2 < 256; ++m2) {
        const float4 yv = *reinterpret_cast<const float4*>(yp);
#pragma unroll
        for (int j = 0; j < 8; ++j) {
            const float tv = tp[j * 32];
            acc[0][j] = fmaf(yv.x, tv, acc[0][j]);
            acc[1][j] = fmaf(yv.y, tv, acc[1][j]);
            acc[2][j] = fmaf(yv.z, tv, acc[2][j]);
            acc[3][j] = fmaf(yv.w, tv, acc[3][j]);
        }
        yp += 512; tp += L_TOT;
    }

    float* op = out + (((size_t)b * 3 + h) * 512 + o0 + os * 4) * L_TOT + l0 + ls;
#pragma unroll
    for (int a = 0; a < 4; ++a)
#pragma unroll
        for (int j = 0; j < 8; ++j)
            op[(size_t)a * L_TOT + j * 32] = acc[a][j];
}

extern "C" void kernel_launch(void* const* d_in, const int* in_sizes, int n_in,
                              void* d_out, int out_size, void* d_ws, size_t ws_size,
                              hipStream_t stream) {
    const float* q     = (const float*)d_in[0];
    const float* w_re  = (const float*)d_in[1];
    const float* w_im  = (const float*)d_in[2];
    const int*   index = (const int*)d_in[3];
    float* out = (float*)d_out;

    float* ws = (float*)d_ws;
    float* T2 = ws;                       // 1,048,576 floats
    float* Tt = ws + 1048576;             // 1,048,576 floats
    float* X  = ws + 2097152;             // 6,291,456 floats
    float* Yt = ws + 8388608;             // 6,291,456 floats

    build_t2<<<4096, 256, 0, stream>>>(index, T2);
    build_tt<<<4096, 256, 0, stream>>>(index, Tt);
    stage_a<<<768, 256, 0, stream>>>(q, T2, X);
    stage_b<<<1536, 128, 0, stream>>>(X, w_re, w_im, index, Yt);
    stage_c<<<12288, 256, 0, stream>>>(Yt, Tt, out);
}

// Round 2
// 1294.195 us; speedup vs baseline: 2.5129x; 2.5129x over previous
//
#include <hip/hip_runtime.h>
#include <hip/hip_bf16.h>

// FourierBlock: B=16, L=4096, H=3, E=512, M=128 modes.
// Pipeline:
//   0. trans_q : q[b,l,ch] f32 -> qt[b,ch,l] bf16   (qt stored in d_out, dead space)
//   1. build_ta: T_A[m2=256][l=4096] bf16  (cos / -sin interleaved)
//   2. build_tc: T_C[l=4096][m2=256] bf16  (scale c_m/L folded in)
//   3. gemm<0> : X[h,b,i,m2] f32 = qt[b,ch,:] . T_A^T   (MFMA bf16, K=4096)
//   4. stage_b : Ybf[(b,h,o)][m2] bf16 = complex channel mix (fp32 VALU)
//   5. gemm<1> : out[(b,h,o)][l] f32 = Ybf . T_C^T       (MFMA bf16, K=256)
//
// ws (floats/bytes):
//   X   : 3*16*512*256 f32   = 25,165,824 B  @ 0
//   Ybf : 24576*256 bf16     = 12,582,912 B  @ 25165824
//   T_A : 256*4096 bf16      =  2,097,152 B  @ 37748736
//   T_C : 4096*256 bf16      =  2,097,152 B  @ 39845888    (total 40 MB)

#define L_TOT 4096

typedef __attribute__((ext_vector_type(4))) float f32x4;
typedef __attribute__((ext_vector_type(8))) short s16x8;
typedef __attribute__((ext_vector_type(4))) unsigned short u16x4;

__device__ __forceinline__ unsigned short f2bf(float f) {
    unsigned u = __builtin_bit_cast(unsigned, f);
    u = (u + 0x7fffu + ((u >> 16) & 1u)) >> 16;
    return (unsigned short)u;
}

__device__ __forceinline__ void gload_lds16(const void* g, void* l) {
    __builtin_amdgcn_global_load_lds((const __attribute__((address_space(1))) void*)g,
                                     (__attribute__((address_space(3))) void*)l,
                                     16, 0, 0);
}

// ---- transpose + bf16 cast: q[b][l][ch] -> qt[b][ch][l] ----
// grid 24576 = b(16) x lt(64) x ct(24); block 256
__global__ __launch_bounds__(256) void trans_q(const float* __restrict__ q,
                                               unsigned short* __restrict__ qt) {
    __shared__ unsigned short lds[64 * 66];
    const int bid = blockIdx.x;
    const int ct = bid % 24;
    const int lt = (bid / 24) % 64;
    const int b  = bid / (24 * 64);
    const int l0 = lt * 64, c0 = ct * 64;
    const int t = threadIdx.x;

    const int ch_loc = t & 63;
    const int lsub   = t >> 6;          // 0..3
#pragma unroll
    for (int r = 0; r < 16; ++r) {
        const int l_loc = r * 4 + lsub;
        const float v = q[((size_t)b * L_TOT + l0 + l_loc) * 1536 + c0 + ch_loc];
        lds[ch_loc * 66 + l_loc] = f2bf(v);
    }
    __syncthreads();
    const int l4 = (t & 15) * 4;
    const int cr = t >> 4;              // 0..15
#pragma unroll
    for (int r = 0; r < 4; ++r) {
        const int ch_row = r * 16 + cr;
        u16x4 v;
        v.x = lds[ch_row * 66 + l4 + 0];
        v.y = lds[ch_row * 66 + l4 + 1];
        v.z = lds[ch_row * 66 + l4 + 2];
        v.w = lds[ch_row * 66 + l4 + 3];
        *reinterpret_cast<u16x4*>(&qt[((size_t)b * 1536 + c0 + ch_row) * L_TOT + l0 + l4]) = v;
    }
}

// ---- T_A[m2][l]: m2 even = cos, odd = -sin ----
__global__ __launch_bounds__(256) void build_ta(const int* __restrict__ index,
                                                unsigned short* __restrict__ T_A) {
    const int idx = blockIdx.x * 256 + threadIdx.x;   // 1,048,576
    const int m2 = idx >> 12;
    const int l  = idx & (L_TOT - 1);
    const int k  = index[m2 >> 1];
    const int tt = (k * l) & (L_TOT - 1);
    const float x = (float)tt * (1.0f / 2048.0f);
    T_A[idx] = f2bf((m2 & 1) ? -sinpif(x) : cospif(x));
}

// ---- T_C[l][m2]: scale folded: s=(k==0?1:2)/L ----
__global__ __launch_bounds__(256) void build_tc(const int* __restrict__ index,
                                                unsigned short* __restrict__ T_C) {
    const int idx = blockIdx.x * 256 + threadIdx.x;   // 1,048,576
    const int l  = idx >> 8;
    const int m2 = idx & 255;
    const int k  = index[m2 >> 1];
    const int tt = (k * l) & (L_TOT - 1);
    const float x = (float)tt * (1.0f / 2048.0f);
    const float s = (k == 0 ? 1.0f : 2.0f) * (1.0f / (float)L_TOT);
    T_C[idx] = f2bf(s * ((m2 & 1) ? -sinpif(x) : cospif(x)));
}

// ---- MFMA GEMM: C[BMxBN] += A[BMxK] . Bt[BNxK]^T, bf16 in / f32 out ----
// MODE 0 (stage A): BM=64,  grid 768  = b(16) x cht(24) x nt(2), K=4096, lda=4096, ldc=256
// MODE 1 (stage C): BM=128, grid 6144 = mt(192) x nt(32),        K=256,  lda=256,  ldc=4096
template <int MODE>
__global__ __launch_bounds__(256) void gemm_bf16(const unsigned short* __restrict__ A,
                                                 const unsigned short* __restrict__ Bt,
                                                 float* __restrict__ C) {
    constexpr int BM   = (MODE == 0) ? 64 : 128;
    constexpr int BK   = 64;
    constexpr int KTOT = (MODE == 0) ? 4096 : 256;
    constexpr int LDAB = (MODE == 0) ? 4096 : 256;
    constexpr int LDC  = (MODE == 0) ? 256 : 4096;
    constexpr int MFR  = BM / 32;          // frags per wave along M
    constexpr int APASS = BM * 8 / 256;    // 16B units in A tile / 256 threads
    constexpr int BPASS = 4;               // 128*8/256

    __shared__ unsigned short As[BM * BK];
    __shared__ unsigned short Bs[128 * BK];

    const int t = threadIdx.x;
    const int lane = t & 63;
    const int w = t >> 6;
    const int wr = w >> 1, wc = w & 1;

    const unsigned short* Ab;
    const unsigned short* Bb;
    float* Cb;
    if (MODE == 0) {
        const int bid = blockIdx.x;
        const int b = bid / 48;
        const int r = bid % 48;
        const int cht = r >> 1, nt = r & 1;
        const int ch0 = cht * 64;
        const int h = ch0 >> 9, i0 = ch0 & 511;
        Ab = A + ((size_t)b * 1536 + ch0) * 4096;
        Bb = Bt + (size_t)(nt * 128) * 4096;
        Cb = C + (((size_t)h * 16 + b) * 512 + i0) * 256 + nt * 128;
    } else {
        const int mt = blockIdx.x >> 5, nt = blockIdx.x & 31;
        Ab = A + (size_t)mt * 128 * 256;
        Bb = Bt + (size_t)nt * 128 * 256;
        Cb = C + (size_t)mt * 128 * 4096 + nt * 128;
    }

    f32x4 acc[MFR][4];
#pragma unroll
    for (int mi = 0; mi < MFR; ++mi)
#pragma unroll
        for (int ni = 0; ni < 4; ++ni) acc[mi][ni] = (f32x4)0.0f;

    for (int kt = 0; kt < KTOT; kt += BK) {
        __syncthreads();
        // stage A tile [BM][64] with XOR-swizzled source, linear LDS dest
#pragma unroll
        for (int p = 0; p < APASS; ++p) {
            const int u = p * 256 + t;
            const int row = u >> 3, c16 = u & 7;
            const unsigned short* src = Ab + (size_t)row * LDAB + kt + ((c16 ^ (row & 7)) * 8);
            unsigned short* dst = As + (size_t)(p * 256 + w * 64) * 8;
            gload_lds16(src, dst);
        }
#pragma unroll
        for (int p = 0; p < BPASS; ++p) {
            const int u = p * 256 + t;
            const int row = u >> 3, c16 = u & 7;
            const unsigned short* src = Bb + (size_t)row * LDAB + kt + ((c16 ^ (row & 7)) * 8);
            unsigned short* dst = Bs + (size_t)(p * 256 + w * 64) * 8;
            gload_lds16(src, dst);
        }
        __syncthreads();   // compiler emits vmcnt(0) drain before barrier

#pragma unroll
        for (int kk = 0; kk < 2; ++kk) {
            const int c16 = kk * 4 + (lane >> 4);
            s16x8 af[MFR], bfr[4];
#pragma unroll
            for (int mi = 0; mi < MFR; ++mi) {
                const int row = wr * (BM / 2) + mi * 16 + (lane & 15);
                af[mi] = *reinterpret_cast<const s16x8*>(As + row * BK + ((c16 ^ (row & 7)) * 8));
            }
#pragma unroll
            for (int ni = 0; ni < 4; ++ni) {
                const int row = wc * 64 + ni * 16 + (lane & 15);
                bfr[ni] = *reinterpret_cast<const s16x8*>(Bs + row * BK + ((c16 ^ (row & 7)) * 8));
            }
#pragma unroll
            for (int mi = 0; mi < MFR; ++mi)
#pragma unroll
                for (int ni = 0; ni < 4; ++ni)
                    acc[mi][ni] = __builtin_amdgcn_mfma_f32_16x16x32_bf16(af[mi], bfr[ni], acc[mi][ni], 0, 0, 0);
        }
    }

    // epilogue: C/D layout col=lane&15, row=(lane>>4)*4+reg
#pragma unroll
    for (int mi = 0; mi < MFR; ++mi) {
        const int r0 = wr * (BM / 2) + mi * 16 + (lane >> 4) * 4;
#pragma unroll
        for (int ni = 0; ni < 4; ++ni) {
            const int col = wc * 64 + ni * 16 + (lane & 15);
#pragma unroll
            for (int j = 0; j < 4; ++j)
                Cb[(size_t)(r0 + j) * LDC + col] = acc[mi][ni][j];
        }
    }
}

// ---- Stage B: complex channel mix, fp32 VALU, bf16 out ----
// grid 1536 = h(3) x mt(8) x oc(64); block 128 = b(16) x mp(8)
__global__ __launch_bounds__(128) void stage_b(const float* __restrict__ X,
                                               const float* __restrict__ wr,
                                               const float* __restrict__ wi,
                                               unsigned short* __restrict__ Ybf) {
    const int blk = blockIdx.x;
    const int h  = blk >> 9;
    const int mt = (blk >> 6) & 7;
    const int oc = blk & 63;
    const int o0 = oc * 8;
    const int m0 = mt * 16;
    const int t  = threadIdx.x;
    const int b  = t >> 3;
    const int mp = t & 7;
    const int m  = m0 + mp * 2;

    float aR[8][2], aI[8][2];
#pragma unroll
    for (int oi = 0; oi < 8; ++oi) {
        aR[oi][0] = aR[oi][1] = 0.f;
        aI[oi][0] = aI[oi][1] = 0.f;
    }

    const float* xp  = X + ((((size_t)h * 16 + b) * 512) * 128 + m) * 2;
    const float* wrp = wr + ((size_t)h * 512 * 512 + o0) * 128 + m;
    const float* wip = wi + ((size_t)h * 512 * 512 + o0) * 128 + m;

    for (int i = 0; i < 512; ++i) {
        const float4 xv = *reinterpret_cast<const float4*>(xp);  // Xr0 Xi0 Xr1 Xi1
#pragma unroll
        for (int oi = 0; oi < 8; ++oi) {
            const float2 wrv = *reinterpret_cast<const float2*>(wrp + (size_t)oi * 128);
            const float2 wiv = *reinterpret_cast<const float2*>(wip + (size_t)oi * 128);
            aR[oi][0] = fmaf(xv.x, wrv.x, aR[oi][0]);
            aR[oi][0] = fmaf(-xv.y, wiv.x, aR[oi][0]);
            aI[oi][0] = fmaf(xv.x, wiv.x, aI[oi][0]);
            aI[oi][0] = fmaf(xv.y, wrv.x, aI[oi][0]);
            aR[oi][1] = fmaf(xv.z, wrv.y, aR[oi][1]);
            aR[oi][1] = fmaf(-xv.w, wiv.y, aR[oi][1]);
            aI[oi][1] = fmaf(xv.z, wiv.y, aI[oi][1]);
            aI[oi][1] = fmaf(xv.w, wrv.y, aI[oi][1]);
        }
        xp += 256; wrp += 65536; wip += 65536;
    }

    // Ybf[(b*3+h)*512 + o][m2]; m2 rows 2m..2m+3 = (Yr0, Yi0, Yr1, Yi1)
    unsigned short* y0 = Ybf + (((size_t)b * 3 + h) * 512 + o0) * 256 + 2 * m;
#pragma unroll
    for (int oi = 0; oi < 8; ++oi) {
        u16x4 v;
        v.x = f2bf(aR[oi][0]);
        v.y = f2bf(aI[oi][0]);
        v.z = f2bf(aR[oi][1]);
        v.w = f2bf(aI[oi][1]);
        *reinterpret_cast<u16x4*>(y0 + (size_t)oi * 256) = v;
    }
}

extern "C" void kernel_launch(void* const* d_in, const int* in_sizes, int n_in,
                              void* d_out, int out_size, void* d_ws, size_t ws_size,
                              hipStream_t stream) {
    const float* q     = (const float*)d_in[0];
    const float* w_re  = (const float*)d_in[1];
    const float* w_im  = (const float*)d_in[2];
    const int*   index = (const int*)d_in[3];
    float* out = (float*)d_out;

    char* ws = (char*)d_ws;
    float*          X   = (float*)(ws);                         // 25,165,824 B
    unsigned short* Ybf = (unsigned short*)(ws + 25165824);     // 12,582,912 B
    unsigned short* T_A = (unsigned short*)(ws + 37748736);     //  2,097,152 B
    unsigned short* T_C = (unsigned short*)(ws + 39845888);     //  2,097,152 B

    // qt (bf16, 201 MB) lives in d_out; dead before gemm<1> overwrites d_out.
    unsigned short* qt = (unsigned short*)d_out;

    trans_q<<<24576, 256, 0, stream>>>(q, qt);
    build_ta<<<4096, 256, 0, stream>>>(index, T_A);
    build_tc<<<4096, 256, 0, stream>>>(index, T_C);
    gemm_bf16<0><<<768, 256, 0, stream>>>(qt, T_A, X);
    stage_b<<<1536, 128, 0, stream>>>(X, w_re, w_im, Ybf);
    gemm_bf16<1><<<6144, 256, 0, stream>>>(Ybf, T_C, out);
}

// Round 4
// 1194.833 us; speedup vs baseline: 2.7219x; 1.0832x over previous
//
#include <hip/hip_runtime.h>
#include <hip/hip_bf16.h>

// FourierBlock: B=16, L=4096, H=3, E=512, M=128 modes.
// Pipeline:
//   0. trans_q : q[b,l,ch] f32 -> qt[b,ch,l] bf16   (qt stored in d_out, dead space)
//   1. build_ta: T_A[m2=256][l=4096] bf16  (cos / -sin interleaved)
//   2. build_tc: T_C[l=4096][m2=256] bf16  (scale c_m/L folded in HERE ONLY)
//   3. gemm<0> : X[h,b,i,m2] f32 = qt[b,ch,:] . T_A^T   (MFMA bf16, K=4096)
//   4. stage_b : Ybf[(b,h,o)][m2] bf16 = complex channel mix (fp32 VALU, streamed)
//                NOTE: NO scale here — it lives in T_C (round-3 bug was double-scaling)
//   5. gemm<1> : out[(b,h,o)][l] f32 = Ybf . T_C^T       (MFMA bf16, K=256)
//
// ws: X f32 25,165,824 B @0 | Ybf bf16 12,582,912 B @25165824
//     T_A bf16 2,097,152 B @37748736 | T_C bf16 2,097,152 B @39845888

#define L_TOT 4096

typedef __attribute__((ext_vector_type(4))) float f32x4;
typedef __attribute__((ext_vector_type(8))) short s16x8;
typedef __attribute__((ext_vector_type(4))) unsigned short u16x4;

__device__ __forceinline__ unsigned short f2bf(float f) {
    unsigned u = __builtin_bit_cast(unsigned, f);
    u = (u + 0x7fffu + ((u >> 16) & 1u)) >> 16;
    return (unsigned short)u;
}

__device__ __forceinline__ void gload_lds16(const void* g, void* l) {
    __builtin_amdgcn_global_load_lds((const __attribute__((address_space(1))) void*)g,
                                     (__attribute__((address_space(3))) void*)l,
                                     16, 0, 0);
}

// ---- transpose + bf16 cast: q[b][l][ch] -> qt[b][ch][l] ----
__global__ __launch_bounds__(256) void trans_q(const float* __restrict__ q,
                                               unsigned short* __restrict__ qt) {
    __shared__ unsigned short lds[64 * 66];
    const int bid = blockIdx.x;
    const int ct = bid % 24;
    const int lt = (bid / 24) % 64;
    const int b  = bid / (24 * 64);
    const int l0 = lt * 64, c0 = ct * 64;
    const int t = threadIdx.x;

    const int ch_loc = t & 63;
    const int lsub   = t >> 6;
#pragma unroll
    for (int r = 0; r < 16; ++r) {
        const int l_loc = r * 4 + lsub;
        const float v = q[((size_t)b * L_TOT + l0 + l_loc) * 1536 + c0 + ch_loc];
        lds[ch_loc * 66 + l_loc] = f2bf(v);
    }
    __syncthreads();
    const int l4 = (t & 15) * 4;
    const int cr = t >> 4;
#pragma unroll
    for (int r = 0; r < 4; ++r) {
        const int ch_row = r * 16 + cr;
        u16x4 v;
        v.x = lds[ch_row * 66 + l4 + 0];
        v.y = lds[ch_row * 66 + l4 + 1];
        v.z = lds[ch_row * 66 + l4 + 2];
        v.w = lds[ch_row * 66 + l4 + 3];
        *reinterpret_cast<u16x4*>(&qt[((size_t)b * 1536 + c0 + ch_row) * L_TOT + l0 + l4]) = v;
    }
}

__global__ __launch_bounds__(256) void build_ta(const int* __restrict__ index,
                                                unsigned short* __restrict__ T_A) {
    const int idx = blockIdx.x * 256 + threadIdx.x;
    const int m2 = idx >> 12;
    const int l  = idx & (L_TOT - 1);
    const int k  = index[m2 >> 1];
    const int tt = (k * l) & (L_TOT - 1);
    const float x = (float)tt * (1.0f / 2048.0f);
    T_A[idx] = f2bf((m2 & 1) ? -sinpif(x) : cospif(x));
}

__global__ __launch_bounds__(256) void build_tc(const int* __restrict__ index,
                                                unsigned short* __restrict__ T_C) {
    const int idx = blockIdx.x * 256 + threadIdx.x;
    const int l  = idx >> 8;
    const int m2 = idx & 255;
    const int k  = index[m2 >> 1];
    const int tt = (k * l) & (L_TOT - 1);
    const float x = (float)tt * (1.0f / 2048.0f);
    const float s = (k == 0 ? 1.0f : 2.0f) * (1.0f / (float)L_TOT);
    T_C[idx] = f2bf(s * ((m2 & 1) ? -sinpif(x) : cospif(x)));
}

// ---- MFMA GEMM: C[BMxBN] += A[BMxK] . Bt[BNxK]^T, bf16 in / f32 out ----
template <int MODE>
__global__ __launch_bounds__(256) void gemm_bf16(const unsigned short* __restrict__ A,
                                                 const unsigned short* __restrict__ Bt,
                                                 float* __restrict__ C) {
    constexpr int BM   = (MODE == 0) ? 64 : 128;
    constexpr int BK   = 64;
    constexpr int KTOT = (MODE == 0) ? 4096 : 256;
    constexpr int LDAB = (MODE == 0) ? 4096 : 256;
    constexpr int LDC  = (MODE == 0) ? 256 : 4096;
    constexpr int MFR  = BM / 32;
    constexpr int APASS = BM * 8 / 256;
    constexpr int BPASS = 4;

    __shared__ unsigned short As[BM * BK];
    __shared__ unsigned short Bs[128 * BK];

    const int t = threadIdx.x;
    const int lane = t & 63;
    const int w = t >> 6;
    const int wr = w >> 1, wc = w & 1;

    const unsigned short* Ab;
    const unsigned short* Bb;
    float* Cb;
    if (MODE == 0) {
        const int bid = blockIdx.x;
        const int b = bid / 48;
        const int r = bid % 48;
        const int cht = r >> 1, nt = r & 1;
        const int ch0 = cht * 64;
        const int h = ch0 >> 9, i0 = ch0 & 511;
        Ab = A + ((size_t)b * 1536 + ch0) * 4096;
        Bb = Bt + (size_t)(nt * 128) * 4096;
        Cb = C + (((size_t)h * 16 + b) * 512 + i0) * 256 + nt * 128;
    } else {
        const int mt = blockIdx.x >> 5, nt = blockIdx.x & 31;
        Ab = A + (size_t)mt * 128 * 256;
        Bb = Bt + (size_t)nt * 128 * 256;
        Cb = C + (size_t)mt * 128 * 4096 + nt * 128;
    }

    f32x4 acc[MFR][4];
#pragma unroll
    for (int mi = 0; mi < MFR; ++mi)
#pragma unroll
        for (int ni = 0; ni < 4; ++ni) acc[mi][ni] = (f32x4)0.0f;

    for (int kt = 0; kt < KTOT; kt += BK) {
        __syncthreads();
#pragma unroll
        for (int p = 0; p < APASS; ++p) {
            const int u = p * 256 + t;
            const int row = u >> 3, c16 = u & 7;
            const unsigned short* src = Ab + (size_t)row * LDAB + kt + ((c16 ^ (row & 7)) * 8);
            unsigned short* dst = As + (size_t)(p * 256 + w * 64) * 8;
            gload_lds16(src, dst);
        }
#pragma unroll
        for (int p = 0; p < BPASS; ++p) {
            const int u = p * 256 + t;
            const int row = u >> 3, c16 = u & 7;
            const unsigned short* src = Bb + (size_t)row * LDAB + kt + ((c16 ^ (row & 7)) * 8);
            unsigned short* dst = Bs + (size_t)(p * 256 + w * 64) * 8;
            gload_lds16(src, dst);
        }
        __syncthreads();

#pragma unroll
        for (int kk = 0; kk < 2; ++kk) {
            const int c16 = kk * 4 + (lane >> 4);
            s16x8 af[MFR], bfr[4];
#pragma unroll
            for (int mi = 0; mi < MFR; ++mi) {
                const int row = wr * (BM / 2) + mi * 16 + (lane & 15);
                af[mi] = *reinterpret_cast<const s16x8*>(As + row * BK + ((c16 ^ (row & 7)) * 8));
            }
#pragma unroll
            for (int ni = 0; ni < 4; ++ni) {
                const int row = wc * 64 + ni * 16 + (lane & 15);
                bfr[ni] = *reinterpret_cast<const s16x8*>(Bs + row * BK + ((c16 ^ (row & 7)) * 8));
            }
#pragma unroll
            for (int mi = 0; mi < MFR; ++mi)
#pragma unroll
                for (int ni = 0; ni < 4; ++ni)
                    acc[mi][ni] = __builtin_amdgcn_mfma_f32_16x16x32_bf16(af[mi], bfr[ni], acc[mi][ni], 0, 0, 0);
        }
    }

#pragma unroll
    for (int mi = 0; mi < MFR; ++mi) {
        const int r0 = wr * (BM / 2) + mi * 16 + (lane >> 4) * 4;
#pragma unroll
        for (int ni = 0; ni < 4; ++ni) {
            const int col = wc * 64 + ni * 16 + (lane & 15);
#pragma unroll
            for (int j = 0; j < 4; ++j)
                Cb[(size_t)(r0 + j) * LDC + col] = acc[mi][ni][j];
        }
    }
}

// ---- Stage B: complex channel mix, fp32 VALU, streaming weights ----
// grid 384 = h(3) x ot(32) x mg(4); block 512 = o_loc(16) x m_loc(32)
// Each weight element read by exactly one lane once; X staged in LDS per
// 8-i chunk via global_load_lds; acc[16 b] complex in regs.
// NO output scale here — irfft scale is folded into T_C.
__global__ __launch_bounds__(512) void stage_b(const float* __restrict__ X,
                                               const float* __restrict__ wr,
                                               const float* __restrict__ wi,
                                               unsigned short* __restrict__ Ybf) {
    __shared__ float Xs[16][8][32][2];   // [b][il][m_loc][re/im] = 32 KB
    const int bid = blockIdx.x;          // 384 = h*128 + ot*4 + mg
    const int mg = bid & 3;
    const int ot = (bid >> 2) & 31;
    const int h  = bid >> 7;
    const int t  = threadIdx.x;
    const int m_loc = t & 31;
    const int o_loc = t >> 5;            // 0..15
    const int o = ot * 16 + o_loc;
    const int m = mg * 32 + m_loc;

    const size_t wbase = (size_t)h * (512 * 512 * 128) + (size_t)o * 128 + m;
    const float* wrp = wr + wbase;
    const float* wip = wi + wbase;

    float aR[16], aI[16];
#pragma unroll
    for (int b = 0; b < 16; ++b) { aR[b] = 0.f; aI[b] = 0.f; }

    for (int ic = 0; ic < 64; ++ic) {
        __syncthreads();
        // stage X[16 b][8 i][64 m2 f32] = 32 KB, linear LDS dest
#pragma unroll
        for (int p = 0; p < 4; ++p) {
            const int u = p * 512 + t;
            const int row = u >> 4;        // b*8 + il
            const int col = u & 15;
            const int b  = row >> 3;
            const int il = row & 7;
            const float* src = X + ((size_t)(h * 16 + b) * 512 + ic * 8 + il) * 256
                               + mg * 64 + col * 4;
            gload_lds16(src, (char*)Xs + (size_t)u * 16);
        }
        __syncthreads();

        float wrv[8], wiv[8];
#pragma unroll
        for (int il = 0; il < 8; ++il) {
            const size_t io = (size_t)(ic * 8 + il) * 65536;
            wrv[il] = wrp[io];
            wiv[il] = wip[io];
        }
#pragma unroll
        for (int il = 0; il < 8; ++il) {
#pragma unroll
            for (int b = 0; b < 16; ++b) {
                const float2 x = *reinterpret_cast<const float2*>(&Xs[b][il][m_loc][0]);
                aR[b] = fmaf(x.x, wrv[il], aR[b]);
                aR[b] = fmaf(-x.y, wiv[il], aR[b]);
                aI[b] = fmaf(x.x, wiv[il], aI[b]);
                aI[b] = fmaf(x.y, wrv[il], aI[b]);
            }
        }
    }

#pragma unroll
    for (int b = 0; b < 16; ++b) {
        const unsigned lo = f2bf(aR[b]);
        const unsigned hi = f2bf(aI[b]);
        const unsigned pack = lo | (hi << 16);
        *reinterpret_cast<unsigned*>(Ybf + ((size_t)(b * 3 + h) * 512 + o) * 256 + 2 * m) = pack;
    }
}

extern "C" void kernel_launch(void* const* d_in, const int* in_sizes, int n_in,
                              void* d_out, int out_size, void* d_ws, size_t ws_size,
                              hipStream_t stream) {
    const float* q     = (const float*)d_in[0];
    const float* w_re  = (const float*)d_in[1];
    const float* w_im  = (const float*)d_in[2];
    const int*   index = (const int*)d_in[3];
    float* out = (float*)d_out;

    char* ws = (char*)d_ws;
    float*          X   = (float*)(ws);
    unsigned short* Ybf = (unsigned short*)(ws + 25165824);
    unsigned short* T_A = (unsigned short*)(ws + 37748736);
    unsigned short* T_C = (unsigned short*)(ws + 39845888);

    unsigned short* qt = (unsigned short*)d_out;

    trans_q<<<24576, 256, 0, stream>>>(q, qt);
    build_ta<<<4096, 256, 0, stream>>>(index, T_A);
    build_tc<<<4096, 256, 0, stream>>>(index, T_C);
    gemm_bf16<0><<<768, 256, 0, stream>>>(qt, T_A, X);
    stage_b<<<384, 512, 0, stream>>>(X, w_re, w_im, Ybf);
    gemm_bf16<1><<<6144, 256, 0, stream>>>(Ybf, T_C, out);
}

// Round 5
// 983.797 us; speedup vs baseline: 3.3058x; 1.2145x over previous
//
#include <hip/hip_runtime.h>
#include <hip/hip_bf16.h>

// FourierBlock: B=16, L=4096, H=3, E=512, M=128 modes.
// Pipeline:
//   0. trans_q : q[b,l,ch] f32 -> qt[b,ch,l] bf16   (qt stored in d_out, dead space)
//   1. build_ta: T_A[m2=256][l=4096] bf16  (cos / -sin interleaved)
//   2. build_tc: T_C[l=4096][m2=256] bf16  (irfft scale c_m/L folded in HERE ONLY)
//   3. gemm<0> : Xbf[h,b,i,m2] bf16 = qt[b,ch,:] . T_A^T   (MFMA bf16, K=4096)
//   4. stage_b : Ybf[(b,h,o)][m2] bf16 = complex channel mix
//                (fp32 VALU, float4 weight streaming, X bf16 from LDS)
//   5. gemm<1> : out[(b,h,o)][l] f32 = Ybf . T_C^T          (MFMA bf16, K=256)
//
// ws: Xbf bf16 12,582,912 B @0 | Ybf bf16 12,582,912 B @25165824
//     T_A bf16 2,097,152 B @37748736 | T_C bf16 2,097,152 B @39845888

#define L_TOT 4096

typedef __attribute__((ext_vector_type(4))) float f32x4;
typedef __attribute__((ext_vector_type(8))) short s16x8;
typedef __attribute__((ext_vector_type(4))) unsigned short u16x4;

__device__ __forceinline__ unsigned short f2bf(float f) {
    unsigned u = __builtin_bit_cast(unsigned, f);
    u = (u + 0x7fffu + ((u >> 16) & 1u)) >> 16;
    return (unsigned short)u;
}

__device__ __forceinline__ void gload_lds16(const void* g, void* l) {
    __builtin_amdgcn_global_load_lds((const __attribute__((address_space(1))) void*)g,
                                     (__attribute__((address_space(3))) void*)l,
                                     16, 0, 0);
}

// ---- transpose + bf16 cast: q[b][l][ch] -> qt[b][ch][l] ----
__global__ __launch_bounds__(256) void trans_q(const float* __restrict__ q,
                                               unsigned short* __restrict__ qt) {
    __shared__ unsigned short lds[64 * 66];
    const int bid = blockIdx.x;
    const int ct = bid % 24;
    const int lt = (bid / 24) % 64;
    const int b  = bid / (24 * 64);
    const int l0 = lt * 64, c0 = ct * 64;
    const int t = threadIdx.x;

    const int ch_loc = t & 63;
    const int lsub   = t >> 6;
#pragma unroll
    for (int r = 0; r < 16; ++r) {
        const int l_loc = r * 4 + lsub;
        const float v = q[((size_t)b * L_TOT + l0 + l_loc) * 1536 + c0 + ch_loc];
        lds[ch_loc * 66 + l_loc] = f2bf(v);
    }
    __syncthreads();
    const int l4 = (t & 15) * 4;
    const int cr = t >> 4;
#pragma unroll
    for (int r = 0; r < 4; ++r) {
        const int ch_row = r * 16 + cr;
        u16x4 v;
        v.x = lds[ch_row * 66 + l4 + 0];
        v.y = lds[ch_row * 66 + l4 + 1];
        v.z = lds[ch_row * 66 + l4 + 2];
        v.w = lds[ch_row * 66 + l4 + 3];
        *reinterpret_cast<u16x4*>(&qt[((size_t)b * 1536 + c0 + ch_row) * L_TOT + l0 + l4]) = v;
    }
}

__global__ __launch_bounds__(256) void build_ta(const int* __restrict__ index,
                                                unsigned short* __restrict__ T_A) {
    const int idx = blockIdx.x * 256 + threadIdx.x;
    const int m2 = idx >> 12;
    const int l  = idx & (L_TOT - 1);
    const int k  = index[m2 >> 1];
    const int tt = (k * l) & (L_TOT - 1);
    const float x = (float)tt * (1.0f / 2048.0f);
    T_A[idx] = f2bf((m2 & 1) ? -sinpif(x) : cospif(x));
}

__global__ __launch_bounds__(256) void build_tc(const int* __restrict__ index,
                                                unsigned short* __restrict__ T_C) {
    const int idx = blockIdx.x * 256 + threadIdx.x;
    const int l  = idx >> 8;
    const int m2 = idx & 255;
    const int k  = index[m2 >> 1];
    const int tt = (k * l) & (L_TOT - 1);
    const float x = (float)tt * (1.0f / 2048.0f);
    const float s = (k == 0 ? 1.0f : 2.0f) * (1.0f / (float)L_TOT);
    T_C[idx] = f2bf(s * ((m2 & 1) ? -sinpif(x) : cospif(x)));
}

// ---- MFMA GEMM: C[BMxBN] += A[BMxK] . Bt[BNxK]^T, bf16 in ----
// MODE 0: out bf16 (Xbf); MODE 1: out f32 (final output)
template <int MODE>
__global__ __launch_bounds__(256) void gemm_bf16(const unsigned short* __restrict__ A,
                                                 const unsigned short* __restrict__ Bt,
                                                 void* __restrict__ Cv) {
    constexpr int BM   = (MODE == 0) ? 64 : 128;
    constexpr int BK   = 64;
    constexpr int KTOT = (MODE == 0) ? 4096 : 256;
    constexpr int LDAB = (MODE == 0) ? 4096 : 256;
    constexpr int LDC  = (MODE == 0) ? 256 : 4096;
    constexpr int MFR  = BM / 32;
    constexpr int APASS = BM * 8 / 256;
    constexpr int BPASS = 4;

    __shared__ unsigned short As[BM * BK];
    __shared__ unsigned short Bs[128 * BK];

    const int t = threadIdx.x;
    const int lane = t & 63;
    const int w = t >> 6;
    const int wr = w >> 1, wc = w & 1;

    const unsigned short* Ab;
    const unsigned short* Bb;
    size_t cbase;
    if (MODE == 0) {
        const int bid = blockIdx.x;
        const int b = bid / 48;
        const int r = bid % 48;
        const int cht = r >> 1, nt = r & 1;
        const int ch0 = cht * 64;
        const int h = ch0 >> 9, i0 = ch0 & 511;
        Ab = A + ((size_t)b * 1536 + ch0) * 4096;
        Bb = Bt + (size_t)(nt * 128) * 4096;
        cbase = (((size_t)h * 16 + b) * 512 + i0) * 256 + nt * 128;
    } else {
        const int mt = blockIdx.x >> 5, nt = blockIdx.x & 31;
        Ab = A + (size_t)mt * 128 * 256;
        Bb = Bt + (size_t)nt * 128 * 256;
        cbase = (size_t)mt * 128 * 4096 + nt * 128;
    }

    f32x4 acc[MFR][4];
#pragma unroll
    for (int mi = 0; mi < MFR; ++mi)
#pragma unroll
        for (int ni = 0; ni < 4; ++ni) acc[mi][ni] = (f32x4)0.0f;

    for (int kt = 0; kt < KTOT; kt += BK) {
        __syncthreads();
#pragma unroll
        for (int p = 0; p < APASS; ++p) {
            const int u = p * 256 + t;
            const int row = u >> 3, c16 = u & 7;
            const unsigned short* src = Ab + (size_t)row * LDAB + kt + ((c16 ^ (row & 7)) * 8);
            unsigned short* dst = As + (size_t)(p * 256 + w * 64) * 8;
            gload_lds16(src, dst);
        }
#pragma unroll
        for (int p = 0; p < BPASS; ++p) {
            const int u = p * 256 + t;
            const int row = u >> 3, c16 = u & 7;
            const unsigned short* src = Bb + (size_t)row * LDAB + kt + ((c16 ^ (row & 7)) * 8);
            unsigned short* dst = Bs + (size_t)(p * 256 + w * 64) * 8;
            gload_lds16(src, dst);
        }
        __syncthreads();

#pragma unroll
        for (int kk = 0; kk < 2; ++kk) {
            const int c16 = kk * 4 + (lane >> 4);
            s16x8 af[MFR], bfr[4];
#pragma unroll
            for (int mi = 0; mi < MFR; ++mi) {
                const int row = wr * (BM / 2) + mi * 16 + (lane & 15);
                af[mi] = *reinterpret_cast<const s16x8*>(As + row * BK + ((c16 ^ (row & 7)) * 8));
            }
#pragma unroll
            for (int ni = 0; ni < 4; ++ni) {
                const int row = wc * 64 + ni * 16 + (lane & 15);
                bfr[ni] = *reinterpret_cast<const s16x8*>(Bs + row * BK + ((c16 ^ (row & 7)) * 8));
            }
#pragma unroll
            for (int mi = 0; mi < MFR; ++mi)
#pragma unroll
                for (int ni = 0; ni < 4; ++ni)
                    acc[mi][ni] = __builtin_amdgcn_mfma_f32_16x16x32_bf16(af[mi], bfr[ni], acc[mi][ni], 0, 0, 0);
        }
    }

#pragma unroll
    for (int mi = 0; mi < MFR; ++mi) {
        const int r0 = wr * (BM / 2) + mi * 16 + (lane >> 4) * 4;
#pragma unroll
        for (int ni = 0; ni < 4; ++ni) {
            const int col = wc * 64 + ni * 16 + (lane & 15);
#pragma unroll
            for (int j = 0; j < 4; ++j) {
                if constexpr (MODE == 0) {
                    ((unsigned short*)Cv)[cbase + (size_t)(r0 + j) * LDC + col] = f2bf(acc[mi][ni][j]);
                } else {
                    ((float*)Cv)[cbase + (size_t)(r0 + j) * LDC + col] = acc[mi][ni][j];
                }
            }
        }
    }
}

// ---- Stage B: complex channel mix, fp32 VALU, float4 weight streaming ----
// grid 384 = h(3) x ot(128, 4 o each); block 512 = 8 waves
// wave w: o-pair = w&1 (o = ot*4 + (w&1)*2 + {0,1}); b-quad = w>>1
// lane: m4 = lane&31 (m = m4*4..+3), h1 = lane>>5 -> b = (w>>1)*4 + h1*2 + {0,1}
// Per 4-i chunk: stage Xbf[16 b][4 i][256 m2] (32 KB) via global_load_lds.
// Per i per thread: 4x float4 W loads, 2x ds_read_b128 X, 64 FMA.
__global__ __launch_bounds__(512) void stage_b(const unsigned short* __restrict__ Xbf,
                                               const float* __restrict__ wr,
                                               const float* __restrict__ wi,
                                               unsigned short* __restrict__ Ybf) {
    __shared__ unsigned short Xs[16 * 4 * 256];   // [b][il][m2] = 32 KB
    const int bid = blockIdx.x;          // 384 = h*128 + ot
    const int ot  = bid & 127;
    const int h   = bid >> 7;
    const int t   = threadIdx.x;
    const int lane = t & 63;
    const int w    = t >> 6;
    const int m4   = lane & 31;
    const int h1   = lane >> 5;
    const int b0   = (w >> 1) * 4 + h1 * 2;      // b0, b0+1
    const int o    = ot * 4 + (w & 1) * 2;       // o, o+1

    const size_t wbase = (size_t)h * 33554432 + (size_t)o * 128 + m4 * 4;
    const float* wrp = wr + wbase;
    const float* wip = wi + wbase;
    const unsigned short* xsrc = Xbf + (size_t)h * 16 * 512 * 256;  // [b][i][m2]

    float aR[2][4][2], aI[2][4][2];
#pragma unroll
    for (int bb = 0; bb < 2; ++bb)
#pragma unroll
        for (int j = 0; j < 4; ++j) {
            aR[bb][j][0] = aR[bb][j][1] = 0.f;
            aI[bb][j][0] = aI[bb][j][1] = 0.f;
        }

    for (int ic = 0; ic < 128; ++ic) {
        const int i0 = ic * 4;
        __syncthreads();
        // stage 32 KB: u in 16B units; layout [b][il][32 x 16B]
#pragma unroll
        for (int p = 0; p < 4; ++p) {
            const int u = p * 512 + t;
            const int b    = u >> 7;
            const int il   = (u >> 5) & 3;
            const int s16  = u & 31;
            const unsigned short* src = xsrc + ((size_t)b * 512 + i0 + il) * 256 + s16 * 8;
            gload_lds16(src, (char*)Xs + (size_t)u * 16);
        }
        __syncthreads();

#pragma unroll
        for (int il = 0; il < 4; ++il) {
            const size_t io = (size_t)(i0 + il) * 65536;
            const float4 w_r0 = *reinterpret_cast<const float4*>(wrp + io);
            const float4 w_r1 = *reinterpret_cast<const float4*>(wrp + io + 128);
            const float4 w_i0 = *reinterpret_cast<const float4*>(wip + io);
            const float4 w_i1 = *reinterpret_cast<const float4*>(wip + io + 128);
            const float wr0a[4] = {w_r0.x, w_r0.y, w_r0.z, w_r0.w};
            const float wr1a[4] = {w_r1.x, w_r1.y, w_r1.z, w_r1.w};
            const float wi0a[4] = {w_i0.x, w_i0.y, w_i0.z, w_i0.w};
            const float wi1a[4] = {w_i1.x, w_i1.y, w_i1.z, w_i1.w};
#pragma unroll
            for (int bb = 0; bb < 2; ++bb) {
                const uint4 xv = *reinterpret_cast<const uint4*>(
                    (const char*)Xs + (((b0 + bb) * 4 + il) * 256 + m4 * 8) * 2);
                const unsigned xa[4] = {xv.x, xv.y, xv.z, xv.w};
#pragma unroll
                for (int j = 0; j < 4; ++j) {
                    const float xr = __builtin_bit_cast(float, xa[j] << 16);
                    const float xi = __builtin_bit_cast(float, xa[j] & 0xffff0000u);
                    aR[bb][j][0] = fmaf(xr, wr0a[j], aR[bb][j][0]);
                    aR[bb][j][0] = fmaf(-xi, wi0a[j], aR[bb][j][0]);
                    aI[bb][j][0] = fmaf(xr, wi0a[j], aI[bb][j][0]);
                    aI[bb][j][0] = fmaf(xi, wr0a[j], aI[bb][j][0]);
                    aR[bb][j][1] = fmaf(xr, wr1a[j], aR[bb][j][1]);
                    aR[bb][j][1] = fmaf(-xi, wi1a[j], aR[bb][j][1]);
                    aI[bb][j][1] = fmaf(xr, wi1a[j], aI[bb][j][1]);
                    aI[bb][j][1] = fmaf(xi, wr1a[j], aI[bb][j][1]);
                }
            }
        }
    }

    // Ybf[(b*3+h)*512 + o][m2]: u32 col = m (= m4*4+j), 16B vector per (b,o)
#pragma unroll
    for (int bb = 0; bb < 2; ++bb)
#pragma unroll
        for (int oo = 0; oo < 2; ++oo) {
            const size_t row = ((size_t)(b0 + bb) * 3 + h) * 512 + o + oo;
            uint4 pk;
            pk.x = f2bf(aR[bb][0][oo]) | ((unsigned)f2bf(aI[bb][0][oo]) << 16);
            pk.y = f2bf(aR[bb][1][oo]) | ((unsigned)f2bf(aI[bb][1][oo]) << 16);
            pk.z = f2bf(aR[bb][2][oo]) | ((unsigned)f2bf(aI[bb][2][oo]) << 16);
            pk.w = f2bf(aR[bb][3][oo]) | ((unsigned)f2bf(aI[bb][3][oo]) << 16);
            *reinterpret_cast<uint4*>(reinterpret_cast<char*>(Ybf) + row * 512 + m4 * 16) = pk;
        }
}

extern "C" void kernel_launch(void* const* d_in, const int* in_sizes, int n_in,
                              void* d_out, int out_size, void* d_ws, size_t ws_size,
                              hipStream_t stream) {
    const float* q     = (const float*)d_in[0];
    const float* w_re  = (const float*)d_in[1];
    const float* w_im  = (const float*)d_in[2];
    const int*   index = (const int*)d_in[3];

    char* ws = (char*)d_ws;
    unsigned short* Xbf = (unsigned short*)(ws);                // 12,582,912 B
    unsigned short* Ybf = (unsigned short*)(ws + 25165824);     // 12,582,912 B
    unsigned short* T_A = (unsigned short*)(ws + 37748736);
    unsigned short* T_C = (unsigned short*)(ws + 39845888);

    unsigned short* qt = (unsigned short*)d_out;  // dead until gemm<1> overwrites

    trans_q<<<24576, 256, 0, stream>>>(q, qt);
    build_ta<<<4096, 256, 0, stream>>>(index, T_A);
    build_tc<<<4096, 256, 0, stream>>>(index, T_C);
    gemm_bf16<0><<<768, 256, 0, stream>>>(qt, T_A, (void*)Xbf);
    stage_b<<<384, 512, 0, stream>>>(Xbf, w_re, w_im, Ybf);
    gemm_bf16<1><<<6144, 256, 0, stream>>>(Ybf, T_C, (void*)d_out);
}

// Round 6
// 696.567 us; speedup vs baseline: 4.6689x; 1.4123x over previous
//
#include <hip/hip_runtime.h>
#include <hip/hip_bf16.h>

// FourierBlock: B=16, L=4096, H=3, E=512, M=128 modes.
// Pipeline:
//   0. trans_q : q[b,l,ch] f32 -> qt[b,ch,l] bf16   (qt stored in d_out, dead space)
//   1. build_ta: T_A[m2=256][l=4096] bf16  (cos / -sin interleaved)
//   2. build_tc: T_C[l=4096][m2=256] bf16  (irfft scale c_m/L folded in HERE ONLY)
//   3. gemm<0> : Xbf[h,b,i,m2] bf16 = qt[b,ch,:] . T_A^T   (MFMA bf16, K=4096)
//   4. stage_b : Ybf[(b,h,o)][m2] bf16 = complex channel mix
//                (barrier-free fp32 VALU streaming; X direct from L2, no LDS)
//   5. gemm<1> : out[(b,h,o)][l] f32 = Ybf . T_C^T          (MFMA bf16, K=256)
//
// ws: Xbf bf16 12,582,912 B @0 | Ybf bf16 12,582,912 B @25165824
//     T_A bf16 2,097,152 B @37748736 | T_C bf16 2,097,152 B @39845888

#define L_TOT 4096

typedef __attribute__((ext_vector_type(4))) float f32x4;
typedef __attribute__((ext_vector_type(4))) unsigned u32x4;
typedef __attribute__((ext_vector_type(8))) short s16x8;
typedef __attribute__((ext_vector_type(4))) unsigned short u16x4;

__device__ __forceinline__ unsigned short f2bf(float f) {
    unsigned u = __builtin_bit_cast(unsigned, f);
    u = (u + 0x7fffu + ((u >> 16) & 1u)) >> 16;
    return (unsigned short)u;
}

__device__ __forceinline__ void gload_lds16(const void* g, void* l) {
    __builtin_amdgcn_global_load_lds((const __attribute__((address_space(1))) void*)g,
                                     (__attribute__((address_space(3))) void*)l,
                                     16, 0, 0);
}

// ---- transpose + bf16 cast: q[b][l][ch] -> qt[b][ch][l] ----
__global__ __launch_bounds__(256) void trans_q(const float* __restrict__ q,
                                               unsigned short* __restrict__ qt) {
    __shared__ unsigned short lds[64 * 66];
    const int bid = blockIdx.x;
    const int ct = bid % 24;
    const int lt = (bid / 24) % 64;
    const int b  = bid / (24 * 64);
    const int l0 = lt * 64, c0 = ct * 64;
    const int t = threadIdx.x;

    const int ch_loc = t & 63;
    const int lsub   = t >> 6;
#pragma unroll
    for (int r = 0; r < 16; ++r) {
        const int l_loc = r * 4 + lsub;
        const float v = q[((size_t)b * L_TOT + l0 + l_loc) * 1536 + c0 + ch_loc];
        lds[ch_loc * 66 + l_loc] = f2bf(v);
    }
    __syncthreads();
    const int l4 = (t & 15) * 4;
    const int cr = t >> 4;
#pragma unroll
    for (int r = 0; r < 4; ++r) {
        const int ch_row = r * 16 + cr;
        u16x4 v;
        v.x = lds[ch_row * 66 + l4 + 0];
        v.y = lds[ch_row * 66 + l4 + 1];
        v.z = lds[ch_row * 66 + l4 + 2];
        v.w = lds[ch_row * 66 + l4 + 3];
        *reinterpret_cast<u16x4*>(&qt[((size_t)b * 1536 + c0 + ch_row) * L_TOT + l0 + l4]) = v;
    }
}

__global__ __launch_bounds__(256) void build_ta(const int* __restrict__ index,
                                                unsigned short* __restrict__ T_A) {
    const int idx = blockIdx.x * 256 + threadIdx.x;
    const int m2 = idx >> 12;
    const int l  = idx & (L_TOT - 1);
    const int k  = index[m2 >> 1];
    const int tt = (k * l) & (L_TOT - 1);
    const float x = (float)tt * (1.0f / 2048.0f);
    T_A[idx] = f2bf((m2 & 1) ? -sinpif(x) : cospif(x));
}

__global__ __launch_bounds__(256) void build_tc(const int* __restrict__ index,
                                                unsigned short* __restrict__ T_C) {
    const int idx = blockIdx.x * 256 + threadIdx.x;
    const int l  = idx >> 8;
    const int m2 = idx & 255;
    const int k  = index[m2 >> 1];
    const int tt = (k * l) & (L_TOT - 1);
    const float x = (float)tt * (1.0f / 2048.0f);
    const float s = (k == 0 ? 1.0f : 2.0f) * (1.0f / (float)L_TOT);
    T_C[idx] = f2bf(s * ((m2 & 1) ? -sinpif(x) : cospif(x)));
}

// ---- MFMA GEMM: C[BMxBN] += A[BMxK] . Bt[BNxK]^T, bf16 in ----
// MODE 0: out bf16 (Xbf); MODE 1: out f32 (final output)
template <int MODE>
__global__ __launch_bounds__(256) void gemm_bf16(const unsigned short* __restrict__ A,
                                                 const unsigned short* __restrict__ Bt,
                                                 void* __restrict__ Cv) {
    constexpr int BM   = (MODE == 0) ? 64 : 128;
    constexpr int BK   = 64;
    constexpr int KTOT = (MODE == 0) ? 4096 : 256;
    constexpr int LDAB = (MODE == 0) ? 4096 : 256;
    constexpr int LDC  = (MODE == 0) ? 256 : 4096;
    constexpr int MFR  = BM / 32;
    constexpr int APASS = BM * 8 / 256;
    constexpr int BPASS = 4;

    __shared__ unsigned short As[BM * BK];
    __shared__ unsigned short Bs[128 * BK];

    const int t = threadIdx.x;
    const int lane = t & 63;
    const int w = t >> 6;
    const int wr = w >> 1, wc = w & 1;

    const unsigned short* Ab;
    const unsigned short* Bb;
    size_t cbase;
    if (MODE == 0) {
        const int bid = blockIdx.x;
        const int b = bid / 48;
        const int r = bid % 48;
        const int cht = r >> 1, nt = r & 1;
        const int ch0 = cht * 64;
        const int h = ch0 >> 9, i0 = ch0 & 511;
        Ab = A + ((size_t)b * 1536 + ch0) * 4096;
        Bb = Bt + (size_t)(nt * 128) * 4096;
        cbase = (((size_t)h * 16 + b) * 512 + i0) * 256 + nt * 128;
    } else {
        const int mt = blockIdx.x >> 5, nt = blockIdx.x & 31;
        Ab = A + (size_t)mt * 128 * 256;
        Bb = Bt + (size_t)nt * 128 * 256;
        cbase = (size_t)mt * 128 * 4096 + nt * 128;
    }

    f32x4 acc[MFR][4];
#pragma unroll
    for (int mi = 0; mi < MFR; ++mi)
#pragma unroll
        for (int ni = 0; ni < 4; ++ni) acc[mi][ni] = (f32x4)0.0f;

    for (int kt = 0; kt < KTOT; kt += BK) {
        __syncthreads();
#pragma unroll
        for (int p = 0; p < APASS; ++p) {
            const int u = p * 256 + t;
            const int row = u >> 3, c16 = u & 7;
            const unsigned short* src = Ab + (size_t)row * LDAB + kt + ((c16 ^ (row & 7)) * 8);
            unsigned short* dst = As + (size_t)(p * 256 + w * 64) * 8;
            gload_lds16(src, dst);
        }
#pragma unroll
        for (int p = 0; p < BPASS; ++p) {
            const int u = p * 256 + t;
            const int row = u >> 3, c16 = u & 7;
            const unsigned short* src = Bb + (size_t)row * LDAB + kt + ((c16 ^ (row & 7)) * 8);
            unsigned short* dst = Bs + (size_t)(p * 256 + w * 64) * 8;
            gload_lds16(src, dst);
        }
        __syncthreads();

#pragma unroll
        for (int kk = 0; kk < 2; ++kk) {
            const int c16 = kk * 4 + (lane >> 4);
            s16x8 af[MFR], bfr[4];
#pragma unroll
            for (int mi = 0; mi < MFR; ++mi) {
                const int row = wr * (BM / 2) + mi * 16 + (lane & 15);
                af[mi] = *reinterpret_cast<const s16x8*>(As + row * BK + ((c16 ^ (row & 7)) * 8));
            }
#pragma unroll
            for (int ni = 0; ni < 4; ++ni) {
                const int row = wc * 64 + ni * 16 + (lane & 15);
                bfr[ni] = *reinterpret_cast<const s16x8*>(Bs + row * BK + ((c16 ^ (row & 7)) * 8));
            }
#pragma unroll
            for (int mi = 0; mi < MFR; ++mi)
#pragma unroll
                for (int ni = 0; ni < 4; ++ni)
                    acc[mi][ni] = __builtin_amdgcn_mfma_f32_16x16x32_bf16(af[mi], bfr[ni], acc[mi][ni], 0, 0, 0);
        }
    }

#pragma unroll
    for (int mi = 0; mi < MFR; ++mi) {
        const int r0 = wr * (BM / 2) + mi * 16 + (lane >> 4) * 4;
#pragma unroll
        for (int ni = 0; ni < 4; ++ni) {
            const int col = wc * 64 + ni * 16 + (lane & 15);
#pragma unroll
            for (int j = 0; j < 4; ++j) {
                if constexpr (MODE == 0) {
                    ((unsigned short*)Cv)[cbase + (size_t)(r0 + j) * LDC + col] = f2bf(acc[mi][ni][j]);
                } else {
                    ((float*)Cv)[cbase + (size_t)(r0 + j) * LDC + col] = acc[mi][ni][j];
                }
            }
        }
    }
}

// ---- Stage B v3: barrier-free complex channel mix ----
// grid 768: bid = bq*192 + h*64 + ot  (b-quad siblings congruent mod 8 -> same XCD)
// block 256 = 4 waves; wave w: o = ot*8 + w*2 + {0,1}
// lane: m4 = lane&31 (m = m4*4+j), h1 = lane>>5; b = bq*4 + h1*2 + {0,1}
// Per 2-i body: 8 weight float4 (HBM) + 4 X uint4 (L2) issued up front, 128 FMA.
// No LDS, no __syncthreads.
__global__ __launch_bounds__(256, 4) void stage_b(const unsigned short* __restrict__ Xbf,
                                                  const float* __restrict__ wr,
                                                  const float* __restrict__ wi,
                                                  unsigned short* __restrict__ Ybf) {
    const int bid = blockIdx.x;
    const int ot  = bid & 63;
    const int tmp = bid >> 6;          // = bq*3 + h
    const int h   = tmp % 3;
    const int bq  = tmp / 3;
    const int t    = threadIdx.x;
    const int lane = t & 63;
    const int w    = t >> 6;
    const int m4   = lane & 31;
    const int h1   = lane >> 5;
    const int b0   = bq * 4 + h1 * 2;          // b0, b0+1
    const int o    = ot * 8 + w * 2;           // o, o+1

    const size_t wbase = (size_t)h * 33554432 + (size_t)o * 128 + m4 * 4;
    const float* wrp = wr + wbase;             // + i*65536; o+1 -> +128
    const float* wip = wi + wbase;
    const unsigned short* x0 = Xbf + (size_t)(h * 16 + b0) * 512 * 256 + m4 * 8;  // + i*256; b+1 -> +131072

    float aR[2][2][4], aI[2][2][4];            // [b][o][m]
#pragma unroll
    for (int bb = 0; bb < 2; ++bb)
#pragma unroll
        for (int oo = 0; oo < 2; ++oo)
#pragma unroll
            for (int j = 0; j < 4; ++j) { aR[bb][oo][j] = 0.f; aI[bb][oo][j] = 0.f; }

#pragma unroll 1
    for (int i = 0; i < 512; i += 2) {
        // issue all loads first: weights (HBM) then X (L2-resident)
        f32x4 wrv[2][2], wiv[2][2];            // [istep][o]
        u32x4 xv[2][2];                        // [istep][b]
#pragma unroll
        for (int s = 0; s < 2; ++s) {
            const size_t io = (size_t)(i + s) * 65536;
            wrv[s][0] = *reinterpret_cast<const f32x4*>(wrp + io);
            wrv[s][1] = *reinterpret_cast<const f32x4*>(wrp + io + 128);
            wiv[s][0] = *reinterpret_cast<const f32x4*>(wip + io);
            wiv[s][1] = *reinterpret_cast<const f32x4*>(wip + io + 128);
        }
#pragma unroll
        for (int s = 0; s < 2; ++s) {
            const size_t xo = (size_t)(i + s) * 256;
            xv[s][0] = *reinterpret_cast<const u32x4*>(x0 + xo);
            xv[s][1] = *reinterpret_cast<const u32x4*>(x0 + 131072 + xo);
        }
#pragma unroll
        for (int s = 0; s < 2; ++s)
#pragma unroll
            for (int bb = 0; bb < 2; ++bb) {
#pragma unroll
                for (int j = 0; j < 4; ++j) {
                    const unsigned xu = xv[s][bb][j];
                    const float xr = __builtin_bit_cast(float, xu << 16);
                    const float xi = __builtin_bit_cast(float, xu & 0xffff0000u);
#pragma unroll
                    for (int oo = 0; oo < 2; ++oo) {
                        const float wrj = wrv[s][oo][j];
                        const float wij = wiv[s][oo][j];
                        aR[bb][oo][j] = fmaf(xr, wrj, aR[bb][oo][j]);
                        aR[bb][oo][j] = fmaf(-xi, wij, aR[bb][oo][j]);
                        aI[bb][oo][j] = fmaf(xr, wij, aI[bb][oo][j]);
                        aI[bb][oo][j] = fmaf(xi, wrj, aI[bb][oo][j]);
                    }
                }
            }
    }

    // Ybf[(b*3+h)*512 + o][m2]: 16B vector per (b,o) at byte col m4*16
#pragma unroll
    for (int bb = 0; bb < 2; ++bb)
#pragma unroll
        for (int oo = 0; oo < 2; ++oo) {
            const size_t row = ((size_t)(b0 + bb) * 3 + h) * 512 + o + oo;
            uint4 pk;
            pk.x = f2bf(aR[bb][oo][0]) | ((unsigned)f2bf(aI[bb][oo][0]) << 16);
            pk.y = f2bf(aR[bb][oo][1]) | ((unsigned)f2bf(aI[bb][oo][1]) << 16);
            pk.z = f2bf(aR[bb][oo][2]) | ((unsigned)f2bf(aI[bb][oo][2]) << 16);
            pk.w = f2bf(aR[bb][oo][3]) | ((unsigned)f2bf(aI[bb][oo][3]) << 16);
            *reinterpret_cast<uint4*>(reinterpret_cast<char*>(Ybf) + row * 512 + m4 * 16) = pk;
        }
}

extern "C" void kernel_launch(void* const* d_in, const int* in_sizes, int n_in,
                              void* d_out, int out_size, void* d_ws, size_t ws_size,
                              hipStream_t stream) {
    const float* q     = (const float*)d_in[0];
    const float* w_re  = (const float*)d_in[1];
    const float* w_im  = (const float*)d_in[2];
    const int*   index = (const int*)d_in[3];

    char* ws = (char*)d_ws;
    unsigned short* Xbf = (unsigned short*)(ws);                // 12,582,912 B
    unsigned short* Ybf = (unsigned short*)(ws + 25165824);     // 12,582,912 B
    unsigned short* T_A = (unsigned short*)(ws + 37748736);
    unsigned short* T_C = (unsigned short*)(ws + 39845888);

    unsigned short* qt = (unsigned short*)d_out;  // dead until gemm<1> overwrites

    trans_q<<<24576, 256, 0, stream>>>(q, qt);
    build_ta<<<4096, 256, 0, stream>>>(index, T_A);
    build_tc<<<4096, 256, 0, stream>>>(index, T_C);
    gemm_bf16<0><<<768, 256, 0, stream>>>(qt, T_A, (void*)Xbf);
    stage_b<<<768, 256, 0, stream>>>(Xbf, w_re, w_im, Ybf);
    gemm_bf16<1><<<6144, 256, 0, stream>>>(Ybf, T_C, (void*)d_out);
}